// Round 4
// baseline (228.535 us; speedup 1.0000x reference)
//
#include <hip/hip_runtime.h>

#define N_VOX  150000
#define KNBR   27
#define CIN    32
#define COUT   64
#define NBUCKET 64
#define NEG_SLOPE 0.01f
#define EPS 1e-5f

typedef __bf16 bf16x8 __attribute__((ext_vector_type(8)));
typedef float  f32x4  __attribute__((ext_vector_type(4)));

// fused-prep block ranges
#define NB_FEATS 2344   // ceil(N*CIN/8 / 256)
#define NB_IDX    586   // ceil(N/256)
#define NB_W       27   // K*4*64 / 256
#define NB_Z       32   // NBUCKET*2*COUT / 256

// ===========================================================================
// Fused prep: feats->bf16, W->B-frag bf16, (mask,nbr)->idx_t transposed,
// bsums zeroing. One launch, block-uniform branches.
// ===========================================================================
__global__ __launch_bounds__(256) void prep_all(
    const float* __restrict__ feats, const float* __restrict__ W,
    const int* __restrict__ nbr, const int* __restrict__ mask,
    __bf16* __restrict__ fb, __bf16* __restrict__ Wp,
    int* __restrict__ idxt, float* __restrict__ bsums, int do_idx)
{
    const int t = threadIdx.x;
    int b = blockIdx.x;

    if (b < NB_FEATS) {                       // feats f32 -> bf16
        const int i = b * 256 + t;
        if (i < N_VOX * CIN / 8) {
            const float4* p = reinterpret_cast<const float4*>(feats) + (size_t)i * 2;
            const float4 a = p[0], c = p[1];
            bf16x8 o;
            o[0]=(__bf16)a.x; o[1]=(__bf16)a.y; o[2]=(__bf16)a.z; o[3]=(__bf16)a.w;
            o[4]=(__bf16)c.x; o[5]=(__bf16)c.y; o[6]=(__bf16)c.z; o[7]=(__bf16)c.w;
            reinterpret_cast<bf16x8*>(fb)[i] = o;
        }
        return;
    }
    b -= NB_FEATS;

    if (do_idx) {
        if (b < NB_IDX) {                     // (mask,nbr) -> idx_t[k][n]
            const int n = b * 256 + t;
            if (n < N_VOX) {
                const int* np = nbr + (size_t)n * KNBR;
                const int* mp = mask + (size_t)n * KNBR;
#pragma unroll
                for (int k = 0; k < KNBR; ++k) {
                    const int v = mp[k] ? np[k] : -1;
                    idxt[(size_t)k * N_VOX + n] = v;   // coalesced store
                }
            }
            return;
        }
        b -= NB_IDX;
    }

    if (b < NB_W) {                           // W -> B-fragment order bf16
        const int u = b * 256 + t;            // always < 6912
        const int lane = u & 63, f = u >> 6;
        const int s = f & 3, k = f >> 2;
        const int n = lane & 15, q = lane >> 4;
        const float* src = W + ((size_t)(k * CIN + q * 8) * COUT + s * 16 + n);
        bf16x8 o;
#pragma unroll
        for (int j = 0; j < 8; ++j) o[j] = (__bf16)src[(size_t)j * COUT];
        reinterpret_cast<bf16x8*>(Wp)[u] = o;
        return;
    }
    b -= NB_W;

    const int z = b * 256 + t;                // zero bsums
    if (z < NBUCKET * 2 * COUT) bsums[z] = 0.0f;
}

// ===========================================================================
// conv v2: idx prefetched to registers, per-tap chain = gather -> MFMA only.
// One block = 64 voxels x 64 cols, 4 waves, no LDS, no barriers.
// ===========================================================================
__global__ __launch_bounds__(256, 3) void conv_mfma2(
    const __bf16* __restrict__ fb,            // [N, CIN] bf16
    const __bf16* __restrict__ Wp,            // prepacked B-frags
    const int* __restrict__ idxt,             // [K][N] masked indices
    float* __restrict__ out,                  // [N, COUT]
    float* __restrict__ bsums)                // [NBUCKET][2*COUT]
{
    const int t    = threadIdx.x;
    const int wave = t >> 6;
    const int lane = t & 63;
    const int n16  = lane & 15;
    const int q    = lane >> 4;
    const int arow = blockIdx.x * 64 + wave * 16 + n16;
    const bool rowok = arow < N_VOX;
    const int arc = rowok ? arow : 0;

    // prefetch all tap indices: 27 independent coalesced loads
    int idx[KNBR];
#pragma unroll
    for (int k = 0; k < KNBR; ++k)
        idx[k] = rowok ? idxt[(size_t)k * N_VOX + arc] : -1;

    const bf16x8* __restrict__ bp = reinterpret_cast<const bf16x8*>(Wp);
    const bf16x8 zv = {};

    f32x4 acc0 = {0.f,0.f,0.f,0.f}, acc1 = {0.f,0.f,0.f,0.f};
    f32x4 acc2 = {0.f,0.f,0.f,0.f}, acc3 = {0.f,0.f,0.f,0.f};

#pragma unroll 9
    for (int k = 0; k < KNBR; ++k) {
        const bool v  = idx[k] >= 0;
        const int  ie = v ? idx[k] : 0;
        bf16x8 a = *reinterpret_cast<const bf16x8*>(fb + (size_t)ie * CIN + q * 8);
        if (!v) a = zv;
        const bf16x8 b0 = bp[(k * 4 + 0) * 64 + lane];
        const bf16x8 b1 = bp[(k * 4 + 1) * 64 + lane];
        const bf16x8 b2 = bp[(k * 4 + 2) * 64 + lane];
        const bf16x8 b3 = bp[(k * 4 + 3) * 64 + lane];
        acc0 = __builtin_amdgcn_mfma_f32_16x16x32_bf16(a, b0, acc0, 0, 0, 0);
        acc1 = __builtin_amdgcn_mfma_f32_16x16x32_bf16(a, b1, acc1, 0, 0, 0);
        acc2 = __builtin_amdgcn_mfma_f32_16x16x32_bf16(a, b2, acc2, 0, 0, 0);
        acc3 = __builtin_amdgcn_mfma_f32_16x16x32_bf16(a, b3, acc3, 0, 0, 0);
    }

    // store: C/D layout col=lane&15, row=quad*4+reg (m89-verified)
    const int orow_base = blockIdx.x * 64 + wave * 16 + q * 4;
    f32x4 accs[4] = {acc0, acc1, acc2, acc3};
#pragma unroll
    for (int r = 0; r < 4; ++r) {
        const int orow = orow_base + r;
        if (orow < N_VOX) {
            float* dst = out + (size_t)orow * COUT + n16;
#pragma unroll
            for (int s = 0; s < 4; ++s) dst[s * 16] = accs[s][r];
        }
    }

    // per-channel stats: quad shuffle-reduce + bucketed atomics
    float* dstb = bsums + ((blockIdx.x * 4 + wave) & (NBUCKET - 1)) * (2 * COUT);
#pragma unroll
    for (int s = 0; s < 4; ++s) {
        float ps = accs[s][0] + accs[s][1] + accs[s][2] + accs[s][3];
        float pq = accs[s][0] * accs[s][0] + accs[s][1] * accs[s][1]
                 + accs[s][2] * accs[s][2] + accs[s][3] * accs[s][3];
        ps += __shfl_down(ps, 32); ps += __shfl_down(ps, 16);
        pq += __shfl_down(pq, 32); pq += __shfl_down(pq, 16);
        if (q == 0) {
            atomicAdd(dstb + s * 16 + n16, ps);
            atomicAdd(dstb + COUT + s * 16 + n16, pq);
        }
    }
}

// ===========================================================================
// Fallback conv (R3-verified): direct nbr/mask reads, no idx_t needed.
// ===========================================================================
__global__ __launch_bounds__(256) void conv_mfma1(
    const __bf16* __restrict__ fb, const __bf16* __restrict__ Wp,
    const int* __restrict__ nbr, const int* __restrict__ mask,
    float* __restrict__ out, float* __restrict__ bsums)
{
    const int t = threadIdx.x;
    const int wave = t >> 6, lane = t & 63;
    const int n16 = lane & 15, q = lane >> 4;
    const int arow = blockIdx.x * 64 + wave * 16 + n16;
    const bool rowok = arow < N_VOX;
    const size_t nb = rowok ? (size_t)arow * KNBR : 0;
    const bf16x8* __restrict__ bp = reinterpret_cast<const bf16x8*>(Wp);
    const bf16x8 zv = {};
    f32x4 acc0 = {0.f,0.f,0.f,0.f}, acc1 = {0.f,0.f,0.f,0.f};
    f32x4 acc2 = {0.f,0.f,0.f,0.f}, acc3 = {0.f,0.f,0.f,0.f};
#pragma unroll 3
    for (int k = 0; k < KNBR; ++k) {
        const int mk = mask[nb + k];
        const int ix = nbr[nb + k];
        const bool v = rowok && (mk != 0);
        const int ie = v ? ix : 0;
        bf16x8 a = *reinterpret_cast<const bf16x8*>(fb + (size_t)ie * CIN + q * 8);
        if (!v) a = zv;
        const bf16x8 b0 = bp[(k * 4 + 0) * 64 + lane];
        const bf16x8 b1 = bp[(k * 4 + 1) * 64 + lane];
        const bf16x8 b2 = bp[(k * 4 + 2) * 64 + lane];
        const bf16x8 b3 = bp[(k * 4 + 3) * 64 + lane];
        acc0 = __builtin_amdgcn_mfma_f32_16x16x32_bf16(a, b0, acc0, 0, 0, 0);
        acc1 = __builtin_amdgcn_mfma_f32_16x16x32_bf16(a, b1, acc1, 0, 0, 0);
        acc2 = __builtin_amdgcn_mfma_f32_16x16x32_bf16(a, b2, acc2, 0, 0, 0);
        acc3 = __builtin_amdgcn_mfma_f32_16x16x32_bf16(a, b3, acc3, 0, 0, 0);
    }
    const int orow_base = blockIdx.x * 64 + wave * 16 + q * 4;
    f32x4 accs[4] = {acc0, acc1, acc2, acc3};
#pragma unroll
    for (int r = 0; r < 4; ++r) {
        const int orow = orow_base + r;
        if (orow < N_VOX) {
            float* dst = out + (size_t)orow * COUT + n16;
#pragma unroll
            for (int s = 0; s < 4; ++s) dst[s * 16] = accs[s][r];
        }
    }
    float* dstb = bsums + ((blockIdx.x * 4 + wave) & (NBUCKET - 1)) * (2 * COUT);
#pragma unroll
    for (int s = 0; s < 4; ++s) {
        float ps = accs[s][0] + accs[s][1] + accs[s][2] + accs[s][3];
        float pq = accs[s][0] * accs[s][0] + accs[s][1] * accs[s][1]
                 + accs[s][2] * accs[s][2] + accs[s][3] * accs[s][3];
        ps += __shfl_down(ps, 32); ps += __shfl_down(ps, 16);
        pq += __shfl_down(pq, 32); pq += __shfl_down(pq, 16);
        if (q == 0) {
            atomicAdd(dstb + s * 16 + n16, ps);
            atomicAdd(dstb + COUT + s * 16 + n16, pq);
        }
    }
}

// ===========================================================================
// stats fold + BN apply (unchanged, verified)
// ===========================================================================
__global__ __launch_bounds__(64) void stats_kernel(
    const float* __restrict__ bsums, const float* __restrict__ gamma,
    const float* __restrict__ beta, float* __restrict__ ss)
{
    const int d = threadIdx.x;
    float s = 0.f, q = 0.f;
    for (int b = 0; b < NBUCKET; ++b) {
        s += bsums[b * (2 * COUT) + d];
        q += bsums[b * (2 * COUT) + COUT + d];
    }
    const float inv_n = 1.0f / (float)N_VOX;
    const float mean  = s * inv_n;
    const float var   = q * inv_n - mean * mean;
    const float scale = gamma[d] * rsqrtf(var + EPS);
    ss[d]        = scale;
    ss[COUT + d] = beta[d] - mean * scale;
}

__global__ __launch_bounds__(256) void bn_apply_kernel(
    float* __restrict__ out, const float* __restrict__ ss)
{
    const long i = (long)blockIdx.x * 256 + threadIdx.x;
    const long total4 = (long)N_VOX * COUT / 4;
    if (i >= total4) return;
    float4 v = reinterpret_cast<float4*>(out)[i];
    const int cg = (int)(i & 15);
    const float4 sc = reinterpret_cast<const float4*>(ss)[cg];
    const float4 sh = reinterpret_cast<const float4*>(ss + COUT)[cg];
    float x;
    x = fmaf(v.x, sc.x, sh.x); v.x = (x >= 0.f) ? x : NEG_SLOPE * x;
    x = fmaf(v.y, sc.y, sh.y); v.y = (x >= 0.f) ? x : NEG_SLOPE * x;
    x = fmaf(v.z, sc.z, sh.z); v.z = (x >= 0.f) ? x : NEG_SLOPE * x;
    x = fmaf(v.w, sc.w, sh.w); v.w = (x >= 0.f) ? x : NEG_SLOPE * x;
    reinterpret_cast<float4*>(out)[i] = v;
}

// ===========================================================================
extern "C" void kernel_launch(void* const* d_in, const int* in_sizes, int n_in,
                              void* d_out, int out_size, void* d_ws, size_t ws_size,
                              hipStream_t stream) {
    const float* feats = (const float*)d_in[0];
    const float* W     = (const float*)d_in[1];
    const float* gamma = (const float*)d_in[2];
    const float* beta  = (const float*)d_in[3];
    const int* nbr     = (const int*)d_in[4];
    const int* mask    = (const int*)d_in[5];
    float* out = (float*)d_out;
    char* ws   = (char*)d_ws;

    const size_t fb_bytes  = (size_t)N_VOX * CIN * sizeof(__bf16);       // 9,600,000
    const size_t wp_bytes  = (size_t)KNBR * 4 * 64 * 8 * sizeof(__bf16); // 110,592
    const size_t idx_bytes = (size_t)KNBR * N_VOX * sizeof(int);         // 16,200,000
    const size_t bs_bytes  = (size_t)NBUCKET * 2 * COUT * sizeof(float); // 32,768
    const size_t ss_bytes  = (size_t)2 * COUT * sizeof(float);           // 512
    const long total4 = (long)N_VOX * COUT / 4;
    const int apply_blocks = (int)((total4 + 255) / 256);
    const int conv_blocks  = (N_VOX + 63) / 64;

    __bf16* fb = (__bf16*)ws;
    __bf16* Wp = (__bf16*)(ws + fb_bytes);

    if (ws_size >= fb_bytes + wp_bytes + idx_bytes + bs_bytes + ss_bytes) {
        int*   idxt  = (int*)(ws + fb_bytes + wp_bytes);
        float* bsums = (float*)(ws + fb_bytes + wp_bytes + idx_bytes);
        float* ss    = (float*)(ws + fb_bytes + wp_bytes + idx_bytes + bs_bytes);
        prep_all<<<NB_FEATS + NB_IDX + NB_W + NB_Z, 256, 0, stream>>>(
            feats, W, nbr, mask, fb, Wp, idxt, bsums, 1);
        conv_mfma2<<<conv_blocks, 256, 0, stream>>>(fb, Wp, idxt, out, bsums);
        stats_kernel<<<1, 64, 0, stream>>>(bsums, gamma, beta, ss);
        bn_apply_kernel<<<apply_blocks, 256, 0, stream>>>(out, ss);
    } else {
        float* bsums = (float*)(ws + fb_bytes + wp_bytes);
        float* ss    = (float*)(ws + fb_bytes + wp_bytes + bs_bytes);
        prep_all<<<NB_FEATS + NB_W + NB_Z, 256, 0, stream>>>(
            feats, W, nbr, mask, fb, Wp, nullptr, bsums, 0);
        conv_mfma1<<<conv_blocks, 256, 0, stream>>>(fb, Wp, nbr, mask, out, bsums);
        stats_kernel<<<1, 64, 0, stream>>>(bsums, gamma, beta, ss);
        bn_apply_kernel<<<apply_blocks, 256, 0, stream>>>(out, ss);
    }
}

// Round 5
// 179.320 us; speedup vs baseline: 1.2745x; 1.2745x over previous
//
#include <hip/hip_runtime.h>

#define N_VOX  150000
#define KNBR   27
#define CIN    32
#define COUT   64
#define NBUCKET 64
#define NEG_SLOPE 0.01f
#define EPS 1e-5f
#define APPLY_BLOCKS 1024

typedef __bf16 bf16x8 __attribute__((ext_vector_type(8)));
typedef float  f32x4  __attribute__((ext_vector_type(4)));

// fused-prep block ranges
#define NB_FEATS 2344   // ceil(N*CIN/8 / 256)
#define NB_W       27   // K*4*64 / 256
#define NB_Z       32   // NBUCKET*2*COUT / 256

// ===========================================================================
// Prep: feats->bf16, W->B-frag bf16, bsums zero. One launch.
// ===========================================================================
__global__ __launch_bounds__(256) void prep_all(
    const float* __restrict__ feats, const float* __restrict__ W,
    __bf16* __restrict__ fb, __bf16* __restrict__ Wp,
    float* __restrict__ bsums)
{
    const int t = threadIdx.x;
    int b = blockIdx.x;

    if (b < NB_FEATS) {                       // feats f32 -> bf16
        const int i = b * 256 + t;
        if (i < N_VOX * CIN / 8) {
            const float4* p = reinterpret_cast<const float4*>(feats) + (size_t)i * 2;
            const float4 a = p[0], c = p[1];
            bf16x8 o;
            o[0]=(__bf16)a.x; o[1]=(__bf16)a.y; o[2]=(__bf16)a.z; o[3]=(__bf16)a.w;
            o[4]=(__bf16)c.x; o[5]=(__bf16)c.y; o[6]=(__bf16)c.z; o[7]=(__bf16)c.w;
            reinterpret_cast<bf16x8*>(fb)[i] = o;
        }
        return;
    }
    b -= NB_FEATS;

    if (b < NB_W) {                           // W -> B-fragment order bf16
        const int u = b * 256 + t;            // < 6912
        const int lane = u & 63, f = u >> 6;
        const int s = f & 3, k = f >> 2;
        const int n = lane & 15, q = lane >> 4;
        const float* src = W + ((size_t)(k * CIN + q * 8) * COUT + s * 16 + n);
        bf16x8 o;
#pragma unroll
        for (int j = 0; j < 8; ++j) o[j] = (__bf16)src[(size_t)j * COUT];
        reinterpret_cast<bf16x8*>(Wp)[u] = o;
        return;
    }
    b -= NB_W;

    const int z = b * 256 + t;                // zero bsums
    if (z < NBUCKET * 2 * COUT) bsums[z] = 0.0f;
}

// ===========================================================================
// conv v3: 27 (mask,nbr) pairs prefetched to registers directly from the
// original arrays; per-tap chain = gather -> MFMA. 64 voxels x 64 cols per
// block, 4 waves, no LDS, no barriers.
// ===========================================================================
__global__ __launch_bounds__(256, 3) void conv_mfma3(
    const __bf16* __restrict__ fb,            // [N, CIN] bf16
    const __bf16* __restrict__ Wp,            // prepacked B-frags
    const int* __restrict__ nbr,              // [N, K]
    const int* __restrict__ mask,             // [N, K] int32 bool
    float* __restrict__ out,                  // [N, COUT]
    float* __restrict__ bsums)                // [NBUCKET][2*COUT]
{
    const int t    = threadIdx.x;
    const int wave = t >> 6;
    const int lane = t & 63;
    const int n16  = lane & 15;
    const int q    = lane >> 4;
    const int arow = blockIdx.x * 64 + wave * 16 + n16;
    const bool rowok = arow < N_VOX;
    const size_t nb = (size_t)(rowok ? arow : 0) * KNBR;

    // prefetch all tap indices: independent loads, quads dedup in coalescer
    int idx[KNBR];
#pragma unroll
    for (int k = 0; k < KNBR; ++k) {
        const int m  = mask[nb + k];
        const int ix = nbr[nb + k];
        idx[k] = (rowok && m != 0) ? ix : -1;
    }

    const bf16x8* __restrict__ bp = reinterpret_cast<const bf16x8*>(Wp);
    const bf16x8 zv = {};

    f32x4 acc0 = {0.f,0.f,0.f,0.f}, acc1 = {0.f,0.f,0.f,0.f};
    f32x4 acc2 = {0.f,0.f,0.f,0.f}, acc3 = {0.f,0.f,0.f,0.f};

#pragma unroll 9
    for (int k = 0; k < KNBR; ++k) {
        const bool v  = idx[k] >= 0;
        const int  ie = v ? idx[k] : 0;
        bf16x8 a = *reinterpret_cast<const bf16x8*>(fb + (size_t)ie * CIN + q * 8);
        if (!v) a = zv;
        const bf16x8 b0 = bp[(k * 4 + 0) * 64 + lane];
        const bf16x8 b1 = bp[(k * 4 + 1) * 64 + lane];
        const bf16x8 b2 = bp[(k * 4 + 2) * 64 + lane];
        const bf16x8 b3 = bp[(k * 4 + 3) * 64 + lane];
        acc0 = __builtin_amdgcn_mfma_f32_16x16x32_bf16(a, b0, acc0, 0, 0, 0);
        acc1 = __builtin_amdgcn_mfma_f32_16x16x32_bf16(a, b1, acc1, 0, 0, 0);
        acc2 = __builtin_amdgcn_mfma_f32_16x16x32_bf16(a, b2, acc2, 0, 0, 0);
        acc3 = __builtin_amdgcn_mfma_f32_16x16x32_bf16(a, b3, acc3, 0, 0, 0);
    }

    // store: C/D layout col=lane&15, row=quad*4+reg (m89-verified)
    const int orow_base = blockIdx.x * 64 + wave * 16 + q * 4;
    f32x4 accs[4] = {acc0, acc1, acc2, acc3};
#pragma unroll
    for (int r = 0; r < 4; ++r) {
        const int orow = orow_base + r;
        if (orow < N_VOX) {
            float* dst = out + (size_t)orow * COUT + n16;
#pragma unroll
            for (int s = 0; s < 4; ++s) dst[s * 16] = accs[s][r];
        }
    }

    // per-channel stats: quad shuffle-reduce + bucketed atomics
    float* dstb = bsums + ((blockIdx.x * 4 + wave) & (NBUCKET - 1)) * (2 * COUT);
#pragma unroll
    for (int s = 0; s < 4; ++s) {
        float ps = accs[s][0] + accs[s][1] + accs[s][2] + accs[s][3];
        float pq = accs[s][0] * accs[s][0] + accs[s][1] * accs[s][1]
                 + accs[s][2] * accs[s][2] + accs[s][3] * accs[s][3];
        ps += __shfl_down(ps, 32); ps += __shfl_down(ps, 16);
        pq += __shfl_down(pq, 32); pq += __shfl_down(pq, 16);
        if (q == 0) {
            atomicAdd(dstb + s * 16 + n16, ps);
            atomicAdd(dstb + COUT + s * 16 + n16, pq);
        }
    }
}

// ===========================================================================
// Fused stats-fold + BN apply + LeakyReLU. Each block folds the 32 KB bsums
// (L2-hot) into LDS scale/shift, then grid-strides over out.
// ===========================================================================
__global__ __launch_bounds__(256) void bn_stats_apply(
    float* __restrict__ out, const float* __restrict__ bsums,
    const float* __restrict__ gamma, const float* __restrict__ beta)
{
    __shared__ float s_sc[COUT], s_sh[COUT];
    const int t = threadIdx.x;
    if (t < COUT) {
        float s = 0.f, qq = 0.f;
#pragma unroll 8
        for (int b = 0; b < NBUCKET; ++b) {
            s  += bsums[b * (2 * COUT) + t];
            qq += bsums[b * (2 * COUT) + COUT + t];
        }
        const float inv_n = 1.0f / (float)N_VOX;
        const float mean  = s * inv_n;
        const float var   = qq * inv_n - mean * mean;
        const float scale = gamma[t] * rsqrtf(var + EPS);
        s_sc[t] = scale;
        s_sh[t] = beta[t] - mean * scale;
    }
    __syncthreads();

    const long total4 = (long)N_VOX * COUT / 4;
    const long stride = (long)APPLY_BLOCKS * 256;      // multiple of 16 -> cg invariant
    long i = (long)blockIdx.x * 256 + t;
    const int cg = (int)(i & 15);
    const float4 sc = reinterpret_cast<const float4*>(s_sc)[cg];
    const float4 sh = reinterpret_cast<const float4*>(s_sh)[cg];
    for (; i < total4; i += stride) {
        float4 v = reinterpret_cast<float4*>(out)[i];
        float x;
        x = fmaf(v.x, sc.x, sh.x); v.x = (x >= 0.f) ? x : NEG_SLOPE * x;
        x = fmaf(v.y, sc.y, sh.y); v.y = (x >= 0.f) ? x : NEG_SLOPE * x;
        x = fmaf(v.z, sc.z, sh.z); v.z = (x >= 0.f) ? x : NEG_SLOPE * x;
        x = fmaf(v.w, sc.w, sh.w); v.w = (x >= 0.f) ? x : NEG_SLOPE * x;
        reinterpret_cast<float4*>(out)[i] = v;
    }
}

// ===========================================================================
// Fallback (tiny ws): verified fp32 pipeline from R2
// ===========================================================================
#define TM 64
#define FS 68
__global__ __launch_bounds__(256) void conv_f32(
    const float* __restrict__ feats, const float* __restrict__ W,
    const int* __restrict__ nbr, const int* __restrict__ mask,
    float* __restrict__ out, float* __restrict__ bsums)
{
    __shared__ float f_s[CIN * FS];
    __shared__ float w_s[CIN * COUT];
    const int t = threadIdx.x;
    const int tx = t & 15, ty = t >> 4;
    const int base = blockIdx.x * TM;
    const int gr = t >> 2, cq = t & 3;
    const int n_g = base + gr;
    float acc[4][4];
#pragma unroll
    for (int i = 0; i < 4; ++i)
#pragma unroll
        for (int j = 0; j < 4; ++j) acc[i][j] = 0.0f;
    for (int k = 0; k < KNBR; ++k) {
        int idx = -1;
        if (n_g < N_VOX) {
            const long off = (long)n_g * KNBR + k;
            if (mask[off] != 0) idx = nbr[off];
        }
        float4 fa = make_float4(0.f, 0.f, 0.f, 0.f);
        float4 fbv = fa;
        if (idx >= 0) {
            const float4* fp = reinterpret_cast<const float4*>(feats + (long)idx * CIN + cq * 8);
            fa = fp[0]; fbv = fp[1];
        }
        const float4* wsrc = reinterpret_cast<const float4*>(W + (long)k * CIN * COUT + t * 8);
        const float4 wa = wsrc[0], wb = wsrc[1];
        __syncthreads();
        const int c0 = cq * 8;
        f_s[(c0 + 0) * FS + gr] = fa.x; f_s[(c0 + 1) * FS + gr] = fa.y;
        f_s[(c0 + 2) * FS + gr] = fa.z; f_s[(c0 + 3) * FS + gr] = fa.w;
        f_s[(c0 + 4) * FS + gr] = fbv.x; f_s[(c0 + 5) * FS + gr] = fbv.y;
        f_s[(c0 + 6) * FS + gr] = fbv.z; f_s[(c0 + 7) * FS + gr] = fbv.w;
        reinterpret_cast<float4*>(w_s + t * 8)[0] = wa;
        reinterpret_cast<float4*>(w_s + t * 8)[1] = wb;
        __syncthreads();
#pragma unroll
        for (int c = 0; c < CIN; ++c) {
            const float4 fv = *reinterpret_cast<const float4*>(&f_s[c * FS + ty * 4]);
            const float4 wv = *reinterpret_cast<const float4*>(&w_s[c * COUT + tx * 4]);
            const float fr[4] = {fv.x, fv.y, fv.z, fv.w};
            const float wr[4] = {wv.x, wv.y, wv.z, wv.w};
#pragma unroll
            for (int i = 0; i < 4; ++i)
#pragma unroll
                for (int j = 0; j < 4; ++j)
                    acc[i][j] = fmaf(fr[i], wr[j], acc[i][j]);
        }
    }
#pragma unroll
    for (int i = 0; i < 4; ++i) {
        const int n = base + ty * 4 + i;
        if (n < N_VOX)
            *reinterpret_cast<float4*>(out + (long)n * COUT + tx * 4) =
                make_float4(acc[i][0], acc[i][1], acc[i][2], acc[i][3]);
    }
    float psum[4], psq[4];
#pragma unroll
    for (int j = 0; j < 4; ++j) {
        psum[j] = acc[0][j] + acc[1][j] + acc[2][j] + acc[3][j];
        psq[j]  = acc[0][j] * acc[0][j] + acc[1][j] * acc[1][j]
                + acc[2][j] * acc[2][j] + acc[3][j] * acc[3][j];
    }
    __syncthreads();
    *reinterpret_cast<float4*>(&f_s[ty * 64 + tx * 4]) = make_float4(psum[0], psum[1], psum[2], psum[3]);
    *reinterpret_cast<float4*>(&w_s[ty * 64 + tx * 4]) = make_float4(psq[0], psq[1], psq[2], psq[3]);
    __syncthreads();
    if (t < COUT) {
        float s = 0.f, qq = 0.f;
#pragma unroll
        for (int g = 0; g < 16; ++g) { s += f_s[g * 64 + t]; qq += w_s[g * 64 + t]; }
        float* dst = bsums + (blockIdx.x & (NBUCKET - 1)) * (2 * COUT);
        atomicAdd(dst + t, s);
        atomicAdd(dst + COUT + t, qq);
    }
}

// ===========================================================================
extern "C" void kernel_launch(void* const* d_in, const int* in_sizes, int n_in,
                              void* d_out, int out_size, void* d_ws, size_t ws_size,
                              hipStream_t stream) {
    const float* feats = (const float*)d_in[0];
    const float* W     = (const float*)d_in[1];
    const float* gamma = (const float*)d_in[2];
    const float* beta  = (const float*)d_in[3];
    const int* nbr     = (const int*)d_in[4];
    const int* mask    = (const int*)d_in[5];
    float* out = (float*)d_out;
    char* ws   = (char*)d_ws;

    const size_t fb_bytes = (size_t)N_VOX * CIN * sizeof(__bf16);       // 9,600,000
    const size_t wp_bytes = (size_t)KNBR * 4 * 64 * 8 * sizeof(__bf16); // 110,592
    const size_t bs_bytes = (size_t)NBUCKET * 2 * COUT * sizeof(float); // 32,768
    const int conv_blocks = (N_VOX + 63) / 64;

    if (ws_size >= fb_bytes + wp_bytes + bs_bytes) {
        __bf16* fb   = (__bf16*)ws;
        __bf16* Wp   = (__bf16*)(ws + fb_bytes);
        float* bsums = (float*)(ws + fb_bytes + wp_bytes);
        prep_all<<<NB_FEATS + NB_W + NB_Z, 256, 0, stream>>>(feats, W, fb, Wp, bsums);
        conv_mfma3<<<conv_blocks, 256, 0, stream>>>(fb, Wp, nbr, mask, out, bsums);
        bn_stats_apply<<<APPLY_BLOCKS, 256, 0, stream>>>(out, bsums, gamma, beta);
    } else {
        float* bsums = (float*)ws;
        hipMemsetAsync(bsums, 0, bs_bytes, stream);
        conv_f32<<<(N_VOX + TM - 1) / TM, 256, 0, stream>>>(feats, W, nbr, mask, out, bsums);
        bn_stats_apply<<<APPLY_BLOCKS, 256, 0, stream>>>(out, bsums, gamma, beta);
    }
}

// Round 6
// 170.955 us; speedup vs baseline: 1.3368x; 1.0489x over previous
//
#include <hip/hip_runtime.h>

#define N_VOX  150000
#define KNBR   27
#define CIN    32
#define COUT   64
#define NBUCKET 64
#define NEG_SLOPE 0.01f
#define EPS 1e-5f
#define APPLY_BLOCKS 1024
#define VPB 256            // voxels per conv block (64 per wave)

typedef __bf16 bf16x8 __attribute__((ext_vector_type(8)));
typedef float  f32x4  __attribute__((ext_vector_type(4)));

// fused-prep block ranges
#define NB_FEATS 2344   // ceil(N*CIN/8 / 256)
#define NB_W       27   // K*4*64 / 256
#define NB_Z       32   // NBUCKET*2*COUT / 256

// ===========================================================================
// Prep: feats->bf16, W->B-frag bf16, bsums zero. One launch. (R5-verified)
// ===========================================================================
__global__ __launch_bounds__(256) void prep_all(
    const float* __restrict__ feats, const float* __restrict__ W,
    __bf16* __restrict__ fb, __bf16* __restrict__ Wp,
    float* __restrict__ bsums)
{
    const int t = threadIdx.x;
    int b = blockIdx.x;

    if (b < NB_FEATS) {                       // feats f32 -> bf16
        const int i = b * 256 + t;
        if (i < N_VOX * CIN / 8) {
            const float4* p = reinterpret_cast<const float4*>(feats) + (size_t)i * 2;
            const float4 a = p[0], c = p[1];
            bf16x8 o;
            o[0]=(__bf16)a.x; o[1]=(__bf16)a.y; o[2]=(__bf16)a.z; o[3]=(__bf16)a.w;
            o[4]=(__bf16)c.x; o[5]=(__bf16)c.y; o[6]=(__bf16)c.z; o[7]=(__bf16)c.w;
            reinterpret_cast<bf16x8*>(fb)[i] = o;
        }
        return;
    }
    b -= NB_FEATS;

    if (b < NB_W) {                           // W -> B-fragment order bf16
        const int u = b * 256 + t;            // < 6912
        const int lane = u & 63, f = u >> 6;
        const int s = f & 3, k = f >> 2;
        const int n = lane & 15, q = lane >> 4;
        const float* src = W + ((size_t)(k * CIN + q * 8) * COUT + s * 16 + n);
        bf16x8 o;
#pragma unroll
        for (int j = 0; j < 8; ++j) o[j] = (__bf16)src[(size_t)j * COUT];
        reinterpret_cast<bf16x8*>(Wp)[u] = o;
        return;
    }
    b -= NB_W;

    const int z = b * 256 + t;                // zero bsums
    if (z < NBUCKET * 2 * COUT) bsums[z] = 0.0f;
}

// ===========================================================================
// conv v4: 256 voxels/block, 64 voxels/wave (4 slices of 16).
// idx staged in LDS (coalesced fill, one barrier); per tap: 4 independent
// A-gathers + 4 B-frag loads -> 16 MFMAs. B-traffic amortized 4x vs v3.
// ===========================================================================
__global__ __launch_bounds__(256, 2) void conv_mfma4(
    const __bf16* __restrict__ fb,            // [N, CIN] bf16
    const __bf16* __restrict__ Wp,            // prepacked B-frags
    const int* __restrict__ nbr,              // [N, K]
    const int* __restrict__ mask,             // [N, K] int32 bool
    float* __restrict__ out,                  // [N, COUT]
    float* __restrict__ bsums)                // [NBUCKET][2*COUT]
{
    __shared__ int idx_s[VPB * KNBR];         // 27,648 B

    const int t    = threadIdx.x;
    const int base = blockIdx.x * VPB;

    // ---- cooperative masked-idx fill: 55 KB coalesced stream per block ----
    {
        const size_t gb  = (size_t)base * KNBR;
        const int vlim   = N_VOX - base;
        const int ilim   = (vlim < VPB ? vlim : VPB) * KNBR;
#pragma unroll
        for (int j = 0; j < KNBR; ++j) {
            const int i = t + 256 * j;
            int v = -1;
            if (i < ilim) v = (mask[gb + i] != 0) ? nbr[gb + i] : -1;
            idx_s[i] = v;
        }
    }
    __syncthreads();

    const int wave = t >> 6;
    const int lane = t & 63;
    const int n16  = lane & 15;
    const int q    = lane >> 4;
    const int wb   = wave * 64;               // wave's local voxel base

    const bf16x8* __restrict__ bp = reinterpret_cast<const bf16x8*>(Wp);
    const bf16x8 zv = {};

    // LDS row offsets for the 4 slices this lane reads idx from
    const int r0 = (wb +  0 + n16) * KNBR;
    const int r1 = (wb + 16 + n16) * KNBR;
    const int r2 = (wb + 32 + n16) * KNBR;
    const int r3 = (wb + 48 + n16) * KNBR;

    f32x4 acc[4][4];                          // [slice][col-subtile]
#pragma unroll
    for (int a = 0; a < 4; ++a)
#pragma unroll
        for (int b2 = 0; b2 < 4; ++b2) acc[a][b2] = (f32x4){0.f,0.f,0.f,0.f};

#pragma unroll 3
    for (int k = 0; k < KNBR; ++k) {
        const int i0 = idx_s[r0 + k];
        const int i1 = idx_s[r1 + k];
        const int i2 = idx_s[r2 + k];
        const int i3 = idx_s[r3 + k];

        bf16x8 a0 = *reinterpret_cast<const bf16x8*>(fb + (size_t)(i0 < 0 ? 0 : i0) * CIN + q * 8);
        bf16x8 a1 = *reinterpret_cast<const bf16x8*>(fb + (size_t)(i1 < 0 ? 0 : i1) * CIN + q * 8);
        bf16x8 a2 = *reinterpret_cast<const bf16x8*>(fb + (size_t)(i2 < 0 ? 0 : i2) * CIN + q * 8);
        bf16x8 a3 = *reinterpret_cast<const bf16x8*>(fb + (size_t)(i3 < 0 ? 0 : i3) * CIN + q * 8);
        if (i0 < 0) a0 = zv;
        if (i1 < 0) a1 = zv;
        if (i2 < 0) a2 = zv;
        if (i3 < 0) a3 = zv;

        const bf16x8 b0 = bp[(k * 4 + 0) * 64 + lane];
        const bf16x8 b1 = bp[(k * 4 + 1) * 64 + lane];
        const bf16x8 b2 = bp[(k * 4 + 2) * 64 + lane];
        const bf16x8 b3 = bp[(k * 4 + 3) * 64 + lane];

        acc[0][0] = __builtin_amdgcn_mfma_f32_16x16x32_bf16(a0, b0, acc[0][0], 0, 0, 0);
        acc[0][1] = __builtin_amdgcn_mfma_f32_16x16x32_bf16(a0, b1, acc[0][1], 0, 0, 0);
        acc[0][2] = __builtin_amdgcn_mfma_f32_16x16x32_bf16(a0, b2, acc[0][2], 0, 0, 0);
        acc[0][3] = __builtin_amdgcn_mfma_f32_16x16x32_bf16(a0, b3, acc[0][3], 0, 0, 0);
        acc[1][0] = __builtin_amdgcn_mfma_f32_16x16x32_bf16(a1, b0, acc[1][0], 0, 0, 0);
        acc[1][1] = __builtin_amdgcn_mfma_f32_16x16x32_bf16(a1, b1, acc[1][1], 0, 0, 0);
        acc[1][2] = __builtin_amdgcn_mfma_f32_16x16x32_bf16(a1, b2, acc[1][2], 0, 0, 0);
        acc[1][3] = __builtin_amdgcn_mfma_f32_16x16x32_bf16(a1, b3, acc[1][3], 0, 0, 0);
        acc[2][0] = __builtin_amdgcn_mfma_f32_16x16x32_bf16(a2, b0, acc[2][0], 0, 0, 0);
        acc[2][1] = __builtin_amdgcn_mfma_f32_16x16x32_bf16(a2, b1, acc[2][1], 0, 0, 0);
        acc[2][2] = __builtin_amdgcn_mfma_f32_16x16x32_bf16(a2, b2, acc[2][2], 0, 0, 0);
        acc[2][3] = __builtin_amdgcn_mfma_f32_16x16x32_bf16(a2, b3, acc[2][3], 0, 0, 0);
        acc[3][0] = __builtin_amdgcn_mfma_f32_16x16x32_bf16(a3, b0, acc[3][0], 0, 0, 0);
        acc[3][1] = __builtin_amdgcn_mfma_f32_16x16x32_bf16(a3, b1, acc[3][1], 0, 0, 0);
        acc[3][2] = __builtin_amdgcn_mfma_f32_16x16x32_bf16(a3, b2, acc[3][2], 0, 0, 0);
        acc[3][3] = __builtin_amdgcn_mfma_f32_16x16x32_bf16(a3, b3, acc[3][3], 0, 0, 0);
    }

    // ---- store: C/D layout col=lane&15, row=quad*4+reg (m89-verified) ----
#pragma unroll
    for (int sl = 0; sl < 4; ++sl) {
        const int orow_b = base + wb + sl * 16 + q * 4;
#pragma unroll
        for (int r = 0; r < 4; ++r) {
            const int orow = orow_b + r;
            if (orow < N_VOX) {
                float* dst = out + (size_t)orow * COUT + n16;
#pragma unroll
                for (int s = 0; s < 4; ++s) dst[s * 16] = acc[sl][s][r];
            }
        }
    }

    // ---- per-channel stats: sum slices in-reg, shuffle quads, atomics ----
    float* dstb = bsums + ((blockIdx.x * 4 + wave) & (NBUCKET - 1)) * (2 * COUT);
#pragma unroll
    for (int s = 0; s < 4; ++s) {
        float ps = 0.f, pq = 0.f;
#pragma unroll
        for (int sl = 0; sl < 4; ++sl)
#pragma unroll
            for (int r = 0; r < 4; ++r) {
                const float x = acc[sl][s][r];
                ps += x; pq += x * x;
            }
        ps += __shfl_down(ps, 32); ps += __shfl_down(ps, 16);
        pq += __shfl_down(pq, 32); pq += __shfl_down(pq, 16);
        if (q == 0) {
            atomicAdd(dstb + s * 16 + n16, ps);
            atomicAdd(dstb + COUT + s * 16 + n16, pq);
        }
    }
}

// ===========================================================================
// Fused stats-fold + BN apply + LeakyReLU (R5-verified)
// ===========================================================================
__global__ __launch_bounds__(256) void bn_stats_apply(
    float* __restrict__ out, const float* __restrict__ bsums,
    const float* __restrict__ gamma, const float* __restrict__ beta)
{
    __shared__ float s_sc[COUT], s_sh[COUT];
    const int t = threadIdx.x;
    if (t < COUT) {
        float s = 0.f, qq = 0.f;
#pragma unroll 8
        for (int b = 0; b < NBUCKET; ++b) {
            s  += bsums[b * (2 * COUT) + t];
            qq += bsums[b * (2 * COUT) + COUT + t];
        }
        const float inv_n = 1.0f / (float)N_VOX;
        const float mean  = s * inv_n;
        const float var   = qq * inv_n - mean * mean;
        const float scale = gamma[t] * rsqrtf(var + EPS);
        s_sc[t] = scale;
        s_sh[t] = beta[t] - mean * scale;
    }
    __syncthreads();

    const long total4 = (long)N_VOX * COUT / 4;
    const long stride = (long)APPLY_BLOCKS * 256;
    long i = (long)blockIdx.x * 256 + t;
    const int cg = (int)(i & 15);
    const float4 sc = reinterpret_cast<const float4*>(s_sc)[cg];
    const float4 sh = reinterpret_cast<const float4*>(s_sh)[cg];
    for (; i < total4; i += stride) {
        float4 v = reinterpret_cast<float4*>(out)[i];
        float x;
        x = fmaf(v.x, sc.x, sh.x); v.x = (x >= 0.f) ? x : NEG_SLOPE * x;
        x = fmaf(v.y, sc.y, sh.y); v.y = (x >= 0.f) ? x : NEG_SLOPE * x;
        x = fmaf(v.z, sc.z, sh.z); v.z = (x >= 0.f) ? x : NEG_SLOPE * x;
        x = fmaf(v.w, sc.w, sh.w); v.w = (x >= 0.f) ? x : NEG_SLOPE * x;
        reinterpret_cast<float4*>(out)[i] = v;
    }
}

// ===========================================================================
// Fallback (tiny ws): verified fp32 pipeline from R2
// ===========================================================================
#define TM 64
#define FS 68
__global__ __launch_bounds__(256) void conv_f32(
    const float* __restrict__ feats, const float* __restrict__ W,
    const int* __restrict__ nbr, const int* __restrict__ mask,
    float* __restrict__ out, float* __restrict__ bsums)
{
    __shared__ float f_s[CIN * FS];
    __shared__ float w_s[CIN * COUT];
    const int t = threadIdx.x;
    const int tx = t & 15, ty = t >> 4;
    const int base = blockIdx.x * TM;
    const int gr = t >> 2, cq = t & 3;
    const int n_g = base + gr;
    float acc[4][4];
#pragma unroll
    for (int i = 0; i < 4; ++i)
#pragma unroll
        for (int j = 0; j < 4; ++j) acc[i][j] = 0.0f;
    for (int k = 0; k < KNBR; ++k) {
        int idx = -1;
        if (n_g < N_VOX) {
            const long off = (long)n_g * KNBR + k;
            if (mask[off] != 0) idx = nbr[off];
        }
        float4 fa = make_float4(0.f, 0.f, 0.f, 0.f);
        float4 fbv = fa;
        if (idx >= 0) {
            const float4* fp = reinterpret_cast<const float4*>(feats + (long)idx * CIN + cq * 8);
            fa = fp[0]; fbv = fp[1];
        }
        const float4* wsrc = reinterpret_cast<const float4*>(W + (long)k * CIN * COUT + t * 8);
        const float4 wa = wsrc[0], wb = wsrc[1];
        __syncthreads();
        const int c0 = cq * 8;
        f_s[(c0 + 0) * FS + gr] = fa.x; f_s[(c0 + 1) * FS + gr] = fa.y;
        f_s[(c0 + 2) * FS + gr] = fa.z; f_s[(c0 + 3) * FS + gr] = fa.w;
        f_s[(c0 + 4) * FS + gr] = fbv.x; f_s[(c0 + 5) * FS + gr] = fbv.y;
        f_s[(c0 + 6) * FS + gr] = fbv.z; f_s[(c0 + 7) * FS + gr] = fbv.w;
        reinterpret_cast<float4*>(w_s + t * 8)[0] = wa;
        reinterpret_cast<float4*>(w_s + t * 8)[1] = wb;
        __syncthreads();
#pragma unroll
        for (int c = 0; c < CIN; ++c) {
            const float4 fv = *reinterpret_cast<const float4*>(&f_s[c * FS + ty * 4]);
            const float4 wv = *reinterpret_cast<const float4*>(&w_s[c * COUT + tx * 4]);
            const float fr[4] = {fv.x, fv.y, fv.z, fv.w};
            const float wr[4] = {wv.x, wv.y, wv.z, wv.w};
#pragma unroll
            for (int i = 0; i < 4; ++i)
#pragma unroll
                for (int j = 0; j < 4; ++j)
                    acc[i][j] = fmaf(fr[i], wr[j], acc[i][j]);
        }
    }
#pragma unroll
    for (int i = 0; i < 4; ++i) {
        const int n = base + ty * 4 + i;
        if (n < N_VOX)
            *reinterpret_cast<float4*>(out + (long)n * COUT + tx * 4) =
                make_float4(acc[i][0], acc[i][1], acc[i][2], acc[i][3]);
    }
    float psum[4], psq[4];
#pragma unroll
    for (int j = 0; j < 4; ++j) {
        psum[j] = acc[0][j] + acc[1][j] + acc[2][j] + acc[3][j];
        psq[j]  = acc[0][j] * acc[0][j] + acc[1][j] * acc[1][j]
                + acc[2][j] * acc[2][j] + acc[3][j] * acc[3][j];
    }
    __syncthreads();
    *reinterpret_cast<float4*>(&f_s[ty * 64 + tx * 4]) = make_float4(psum[0], psum[1], psum[2], psum[3]);
    *reinterpret_cast<float4*>(&w_s[ty * 64 + tx * 4]) = make_float4(psq[0], psq[1], psq[2], psq[3]);
    __syncthreads();
    if (t < COUT) {
        float s = 0.f, qq = 0.f;
#pragma unroll
        for (int g = 0; g < 16; ++g) { s += f_s[g * 64 + t]; qq += w_s[g * 64 + t]; }
        float* dst = bsums + (blockIdx.x & (NBUCKET - 1)) * (2 * COUT);
        atomicAdd(dst + t, s);
        atomicAdd(dst + COUT + t, qq);
    }
}

// ===========================================================================
extern "C" void kernel_launch(void* const* d_in, const int* in_sizes, int n_in,
                              void* d_out, int out_size, void* d_ws, size_t ws_size,
                              hipStream_t stream) {
    const float* feats = (const float*)d_in[0];
    const float* W     = (const float*)d_in[1];
    const float* gamma = (const float*)d_in[2];
    const float* beta  = (const float*)d_in[3];
    const int* nbr     = (const int*)d_in[4];
    const int* mask    = (const int*)d_in[5];
    float* out = (float*)d_out;
    char* ws   = (char*)d_ws;

    const size_t fb_bytes = (size_t)N_VOX * CIN * sizeof(__bf16);       // 9,600,000
    const size_t wp_bytes = (size_t)KNBR * 4 * 64 * 8 * sizeof(__bf16); // 110,592
    const size_t bs_bytes = (size_t)NBUCKET * 2 * COUT * sizeof(float); // 32,768

    if (ws_size >= fb_bytes + wp_bytes + bs_bytes) {
        __bf16* fb   = (__bf16*)ws;
        __bf16* Wp   = (__bf16*)(ws + fb_bytes);
        float* bsums = (float*)(ws + fb_bytes + wp_bytes);
        prep_all<<<NB_FEATS + NB_W + NB_Z, 256, 0, stream>>>(feats, W, fb, Wp, bsums);
        conv_mfma4<<<(N_VOX + VPB - 1) / VPB, 256, 0, stream>>>(fb, Wp, nbr, mask, out, bsums);
        bn_stats_apply<<<APPLY_BLOCKS, 256, 0, stream>>>(out, bsums, gamma, beta);
    } else {
        float* bsums = (float*)ws;
        hipMemsetAsync(bsums, 0, bs_bytes, stream);
        conv_f32<<<(N_VOX + TM - 1) / TM, 256, 0, stream>>>(feats, W, nbr, mask, out, bsums);
        bn_stats_apply<<<APPLY_BLOCKS, 256, 0, stream>>>(out, bsums, gamma, beta);
    }
}